// Round 2
// baseline (17810.176 us; speedup 1.0000x reference)
//
#include <hip/hip_runtime.h>
#include <hip/hip_bf16.h>

#define LAYERS 12
#define NHEAD  12
#define DHEAD  64
#define HDIM   768
#define FFDIM  3072
#define SEQ    1024
#define BATCH  4
#define WINSZ  256
#define SPAN   768     // 3*WIN
#define NBLK   4       // SEQ/WIN
#define MTOK   (BATCH*SEQ)   // 4096

// ---------------- block reductions ----------------
__device__ __forceinline__ float wave_sum(float v) {
#pragma unroll
    for (int o = 32; o > 0; o >>= 1) v += __shfl_down(v, o, 64);
    return v;
}
__device__ __forceinline__ float wave_max(float v) {
#pragma unroll
    for (int o = 32; o > 0; o >>= 1) v = fmaxf(v, __shfl_down(v, o, 64));
    return v;
}
// 256-thread block sum (4 waves)
__device__ __forceinline__ float blk_sum256(float v, float* sm) {
    v = wave_sum(v);
    int lane = threadIdx.x & 63, w = threadIdx.x >> 6;
    __syncthreads();
    if (lane == 0) sm[w] = v;
    __syncthreads();
    return sm[0] + sm[1] + sm[2] + sm[3];
}
// 1024-thread block reductions (16 waves)
__device__ __forceinline__ float blk_sum1024(float v, float* sm) {
    v = wave_sum(v);
    int lane = threadIdx.x & 63, w = threadIdx.x >> 6;
    __syncthreads();
    if (lane == 0) sm[w] = v;
    __syncthreads();
    float r = 0.f;
#pragma unroll
    for (int i = 0; i < 16; i++) r += sm[i];
    return r;
}
__device__ __forceinline__ float blk_max1024(float v, float* sm) {
    v = wave_max(v);
    int lane = threadIdx.x & 63, w = threadIdx.x >> 6;
    __syncthreads();
    if (lane == 0) sm[w] = v;
    __syncthreads();
    float r = -1e30f;
#pragma unroll
    for (int i = 0; i < 16; i++) r = fmaxf(r, sm[i]);
    return r;
}

// ---------------- embedding + LN ----------------
__global__ __launch_bounds__(256) void k_embed_ln(
    const float* __restrict__ WE, const float* __restrict__ PE,
    const float* __restrict__ g, const float* __restrict__ bta,
    const int* __restrict__ ids, float* __restrict__ h)
{
    __shared__ float sm[4];
    int tok = blockIdx.x;
    int s = tok & (SEQ - 1);
    int id = ids[tok];
    float x[3];
#pragma unroll
    for (int j = 0; j < 3; j++) {
        int d = threadIdx.x + j * 256;
        x[j] = WE[(size_t)id * HDIM + d] + PE[(size_t)s * HDIM + d];
    }
    float s1 = blk_sum256(x[0] + x[1] + x[2], sm);
    float s2 = blk_sum256(x[0]*x[0] + x[1]*x[1] + x[2]*x[2], sm);
    float mean = s1 * (1.f / HDIM);
    float var  = s2 * (1.f / HDIM) - mean * mean;
    float inv  = rsqrtf(var + 1e-5f);
#pragma unroll
    for (int j = 0; j < 3; j++) {
        int d = threadIdx.x + j * 256;
        h[(size_t)tok * HDIM + d] = (x[j] - mean) * inv * g[d] + bta[d];
    }
}

// ---------------- residual add + LN (in place on h) ----------------
__global__ __launch_bounds__(256) void k_addln(
    float* __restrict__ h, const float* __restrict__ t,
    const float* __restrict__ g, const float* __restrict__ bta)
{
    __shared__ float sm[4];
    int tok = blockIdx.x;
    float x[3];
#pragma unroll
    for (int j = 0; j < 3; j++) {
        int d = threadIdx.x + j * 256;
        x[j] = h[(size_t)tok * HDIM + d] + t[(size_t)tok * HDIM + d];
    }
    float s1 = blk_sum256(x[0] + x[1] + x[2], sm);
    float s2 = blk_sum256(x[0]*x[0] + x[1]*x[1] + x[2]*x[2], sm);
    float mean = s1 * (1.f / HDIM);
    float var  = s2 * (1.f / HDIM) - mean * mean;
    float inv  = rsqrtf(var + 1e-5f);
#pragma unroll
    for (int j = 0; j < 3; j++) {
        int d = threadIdx.x + j * 256;
        h[(size_t)tok * HDIM + d] = (x[j] - mean) * inv * g[d] + bta[d];
    }
}

// ---------------- GEMM: C[M,N] = A[M,K](f32) @ W[K,N](f32) + bias ----------------
// OUTQKV: write C transposed to [B,NH,S,DH]; GELU: exact gelu epilogue
template<int OUTQKV, int GELU>
__global__ __launch_bounds__(256) void k_gemm(
    const float* __restrict__ A, const float* __restrict__ W,
    const float* __restrict__ bias, float* __restrict__ C, int K, int N)
{
    __shared__ float As[32][68];   // [k][row], padded
    __shared__ float Bs[32][64];   // [k][col]
    const int bm = blockIdx.y << 6, bn = blockIdx.x << 6;
    const int tid = threadIdx.x;
    const int tx = tid & 15, ty = tid >> 4;
    float acc[4][4] = {};
    for (int k0 = 0; k0 < K; k0 += 32) {
#pragma unroll
        for (int uu = 0; uu < 2; uu++) {
            int u = tid + uu * 256;
            // A tile 64x32 (512 float4)
            int row = u >> 3, c4 = (u & 7) << 2;
            float4 av = *(const float4*)(A + (size_t)(bm + row) * K + k0 + c4);
            As[c4 + 0][row] = av.x; As[c4 + 1][row] = av.y;
            As[c4 + 2][row] = av.z; As[c4 + 3][row] = av.w;
            // B tile 32x64 (512 float4)
            int brow = u >> 4, bc4 = (u & 15) << 2;
            *(float4*)&Bs[brow][bc4] =
                *(const float4*)(W + (size_t)(k0 + brow) * N + bn + bc4);
        }
        __syncthreads();
#pragma unroll
        for (int kk = 0; kk < 32; kk++) {
            float4 a4 = *(const float4*)&As[kk][ty << 2];
            float4 b4 = *(const float4*)&Bs[kk][tx << 2];
            float ar[4] = {a4.x, a4.y, a4.z, a4.w};
            float br[4] = {b4.x, b4.y, b4.z, b4.w};
#pragma unroll
            for (int i = 0; i < 4; i++)
#pragma unroll
                for (int j = 0; j < 4; j++) acc[i][j] += ar[i] * br[j];
        }
        __syncthreads();
    }
#pragma unroll
    for (int i = 0; i < 4; i++) {
        int m = bm + (ty << 2) + i;
#pragma unroll
        for (int j = 0; j < 4; j++) {
            int n = bn + (tx << 2) + j;
            float v2 = acc[i][j] + bias[n];
            if (GELU) v2 = 0.5f * v2 * (1.f + erff(v2 * 0.70710678118f));
            if (OUTQKV) {
                int b = m >> 10, s = m & 1023;
                int hh = n >> 6, d = n & 63;
                C[(((size_t)b * NHEAD + hh) * SEQ + s) * DHEAD + d] = v2;
            } else {
                C[(size_t)m * N + n] = v2;
            }
        }
    }
}

// ---------------- banded local attention, online softmax ----------------
#define CHROWS 96   // span chunk staged in LDS (8 chunks of 96 = 768)
__global__ __launch_bounds__(256) void k_attn(
    const float* __restrict__ q, const float* __restrict__ k,
    const float* __restrict__ v, const int* __restrict__ mask,
    float* __restrict__ a)
{
    __shared__ float4 ks4[CHROWS * 16];
    __shared__ float4 vs4[CHROWS * 16];
    __shared__ int ms[CHROWS];
    int blk = blockIdx.x;
    int n  = blk & 3;
    int hh = (blk >> 2) % NHEAD;
    int b  = blk / (4 * NHEAD);
    int i  = threadIdx.x;            // query row within block
    int qpos = n * WINSZ + i;
    const float* qrow = q + (((size_t)b * NHEAD + hh) * SEQ + qpos) * DHEAD;
    float4 qv[16];
#pragma unroll
    for (int c = 0; c < 16; c++) qv[c] = ((const float4*)qrow)[c];
    float4 av[16];
#pragma unroll
    for (int c = 0; c < 16; c++) av[c] = make_float4(0.f, 0.f, 0.f, 0.f);
    float mrun = -1e30f, l = 0.f;
    const float* kb = k + ((size_t)b * NHEAD + hh) * SEQ * DHEAD;
    const float* vb = v + ((size_t)b * NHEAD + hh) * SEQ * DHEAD;

    for (int ch = 0; ch < SPAN / CHROWS; ch++) {
        int base = n * WINSZ + ch * CHROWS - WINSZ;  // original k position of row 0
        __syncthreads();
        for (int u = threadIdx.x; u < CHROWS * 16; u += 256) {
            int r = u >> 4, c = u & 15;
            int kpos = base + r;
            bool in = (kpos >= 0) && (kpos < SEQ);
            float4 z = make_float4(0.f, 0.f, 0.f, 0.f);
            ks4[u] = in ? ((const float4*)(kb + (size_t)kpos * DHEAD))[c] : z;
            vs4[u] = in ? ((const float4*)(vb + (size_t)kpos * DHEAD))[c] : z;
        }
        if (threadIdx.x < CHROWS) {
            int kpos = base + threadIdx.x;
            ms[threadIdx.x] = (kpos >= 0 && kpos < SEQ) ? mask[b * SEQ + kpos] : 0;
        }
        __syncthreads();
        for (int r = 0; r < CHROWS; r++) {
            int kj = ch * CHROWS + r;
            int rel = kj - i;
            bool ok = (rel >= 0) && (rel <= 2 * WINSZ) && (ms[r] > 0);
            float s = -1e9f;
            if (ok) {
                float d0 = 0.f;
#pragma unroll
                for (int c = 0; c < 16; c++) {
                    float4 k4 = ks4[r * 16 + c];
                    d0 += qv[c].x * k4.x + qv[c].y * k4.y + qv[c].z * k4.z + qv[c].w * k4.w;
                }
                s = d0 * 0.125f;
            }
            float mn = fmaxf(mrun, s);
            float scale = __expf(mrun - mn);
            float p = __expf(s - mn);
            if (p != 0.f || scale != 1.f) {
                l = l * scale + p;
#pragma unroll
                for (int c = 0; c < 16; c++) {
                    float4 v4 = vs4[r * 16 + c];
                    av[c].x = av[c].x * scale + p * v4.x;
                    av[c].y = av[c].y * scale + p * v4.y;
                    av[c].z = av[c].z * scale + p * v4.z;
                    av[c].w = av[c].w * scale + p * v4.w;
                }
                mrun = mn;
            }
        }
    }
    float inv = 1.f / l;
    float* arow = a + ((size_t)b * SEQ + qpos) * HDIM + hh * DHEAD;
#pragma unroll
    for (int c = 0; c < 16; c++) {
        float4 o;
        o.x = av[c].x * inv; o.y = av[c].y * inv;
        o.z = av[c].z * inv; o.w = av[c].w * inv;
        ((float4*)arow)[c] = o;
    }
}

// ---------------- attention-pool head: sc=h@aw, softmax over S, pooled@Wc+bc ----------------
__global__ __launch_bounds__(1024) void k_pool(
    const float* __restrict__ h, const float* __restrict__ aw,
    const float* __restrict__ Wc, const float* __restrict__ bc,
    float* __restrict__ out)
{
    __shared__ float aws[HDIM];
    __shared__ float ps[SEQ];
    __shared__ float red[16];
    int b = blockIdx.x;
    for (int d = threadIdx.x; d < HDIM; d += 1024) aws[d] = aw[d];
    __syncthreads();
    const float* hb = h + (size_t)b * SEQ * HDIM;
    int s = threadIdx.x;
    float sc = 0.f;
    const float4* hr = (const float4*)(hb + (size_t)s * HDIM);
#pragma unroll 4
    for (int c = 0; c < HDIM / 4; c++) {
        float4 x = hr[c];
        sc += x.x * aws[4*c] + x.y * aws[4*c+1] + x.z * aws[4*c+2] + x.w * aws[4*c+3];
    }
    float mx = blk_max1024(sc, red);
    float e = __expf(sc - mx);
    float tot = blk_sum1024(e, red);
    ps[s] = e / tot;
    __syncthreads();
    float outv = 0.f;
    if (threadIdx.x < HDIM) {
        int d = threadIdx.x;
        float pd = 0.f;
        for (int ss = 0; ss < SEQ; ss++) pd += hb[(size_t)ss * HDIM + d] * ps[ss];
        outv = pd * Wc[d];
    }
    float total = blk_sum1024(outv, red);
    if (threadIdx.x == 0) out[b] = total + bc[0];
}

// ---------------- launcher ----------------
extern "C" void kernel_launch(void* const* d_in, const int* in_sizes, int n_in,
                              void* d_out, int out_size, void* d_ws, size_t ws_size,
                              hipStream_t stream)
{
    const float* WE    = (const float*)d_in[0];
    const float* PE    = (const float*)d_in[1];
    const float* Eg    = (const float*)d_in[2];
    const float* Eb    = (const float*)d_in[3];
    const float* Wq    = (const float*)d_in[4];
    const float* bq    = (const float*)d_in[5];
    const float* Wk    = (const float*)d_in[6];
    const float* bk    = (const float*)d_in[7];
    const float* Wv    = (const float*)d_in[8];
    const float* bv    = (const float*)d_in[9];
    const float* Wo    = (const float*)d_in[10];
    const float* bo    = (const float*)d_in[11];
    const float* g1    = (const float*)d_in[12];
    const float* beta1 = (const float*)d_in[13];
    const float* W1    = (const float*)d_in[14];
    const float* b1    = (const float*)d_in[15];
    const float* W2    = (const float*)d_in[16];
    const float* b2    = (const float*)d_in[17];
    const float* g2    = (const float*)d_in[18];
    const float* beta2 = (const float*)d_in[19];
    const float* aw    = (const float*)d_in[20];
    const float* Wc    = (const float*)d_in[21];
    const float* bc    = (const float*)d_in[22];
    const int* ids     = (const int*)d_in[23];
    const int* msk     = (const int*)d_in[24];

    float* h    = (float*)d_ws;                     // MTOK*H
    float* qb   = h    + (size_t)MTOK * HDIM;       // [B,NH,S,DH]
    float* kbuf = qb   + (size_t)MTOK * HDIM;
    float* vbuf = kbuf + (size_t)MTOK * HDIM;
    float* abuf = vbuf + (size_t)MTOK * HDIM;       // [B,S,H]
    float* tbuf = abuf + (size_t)MTOK * HDIM;       // GEMM temp
    float* mid  = qb;  // aliases q/k/v/a (4*MTOK*H == MTOK*FF), dead by FFN time

    k_embed_ln<<<MTOK, 256, 0, stream>>>(WE, PE, Eg, Eb, ids, h);

    for (int l = 0; l < LAYERS; l++) {
        const float* Wql = Wq + (size_t)l * HDIM * HDIM;
        const float* Wkl = Wk + (size_t)l * HDIM * HDIM;
        const float* Wvl = Wv + (size_t)l * HDIM * HDIM;
        const float* Wol = Wo + (size_t)l * HDIM * HDIM;
        const float* W1l = W1 + (size_t)l * HDIM * FFDIM;
        const float* W2l = W2 + (size_t)l * FFDIM * HDIM;
        dim3 gH(HDIM / 64, MTOK / 64);
        dim3 gF(FFDIM / 64, MTOK / 64);

        k_gemm<1, 0><<<gH, 256, 0, stream>>>(h, Wql, bq + l * HDIM, qb,   HDIM, HDIM);
        k_gemm<1, 0><<<gH, 256, 0, stream>>>(h, Wkl, bk + l * HDIM, kbuf, HDIM, HDIM);
        k_gemm<1, 0><<<gH, 256, 0, stream>>>(h, Wvl, bv + l * HDIM, vbuf, HDIM, HDIM);
        k_attn<<<BATCH * NHEAD * NBLK, 256, 0, stream>>>(qb, kbuf, vbuf, msk, abuf);
        k_gemm<0, 0><<<gH, 256, 0, stream>>>(abuf, Wol, bo + l * HDIM, tbuf, HDIM, HDIM);
        k_addln<<<MTOK, 256, 0, stream>>>(h, tbuf, g1 + l * HDIM, beta1 + l * HDIM);
        k_gemm<0, 1><<<gF, 256, 0, stream>>>(h, W1l, b1 + l * FFDIM, mid, HDIM, FFDIM);
        k_gemm<0, 0><<<gH, 256, 0, stream>>>(mid, W2l, b2 + l * HDIM, tbuf, FFDIM, HDIM);
        k_addln<<<MTOK, 256, 0, stream>>>(h, tbuf, g2 + l * HDIM, beta2 + l * HDIM);
    }

    k_pool<<<BATCH, 1024, 0, stream>>>(h, aw, Wc, bc, (float*)d_out);
}

// Round 4
// 5205.651 us; speedup vs baseline: 3.4213x; 3.4213x over previous
//
#include <hip/hip_runtime.h>
#include <hip/hip_bf16.h>

#define LAYERS 12
#define NHEAD  12
#define DHEAD  64
#define HDIM   768
#define FFDIM  3072
#define SEQ    1024
#define BATCH  4
#define WINSZ  256
#define MTOK   (BATCH*SEQ)          // 4096
#define PLANE  ((size_t)MTOK*HDIM)  // q/k/v plane elems: B*NH*S*DH = 3,145,728

typedef unsigned short u16;
typedef unsigned int   u32;

using f32x4  = __attribute__((ext_vector_type(4))) float;
using bf16x8 = __attribute__((ext_vector_type(8))) short;

__device__ __forceinline__ float bflo(u32 u){ union{u32 i;float f;}x; x.i = u << 16; return x.f; }
__device__ __forceinline__ float bfhi(u32 u){ union{u32 i;float f;}x; x.i = u & 0xffff0000u; return x.f; }
__device__ __forceinline__ u16 f2bf(float f){
    union{float f;u32 u;}x; x.f = f;
    u32 r = x.u + 0x7fffu + ((x.u >> 16) & 1u);   // RTNE
    return (u16)(r >> 16);
}
__device__ __forceinline__ void gload16(const u16* g, u16* l) {
    __builtin_amdgcn_global_load_lds(
        (const __attribute__((address_space(1))) u32*)g,
        (__attribute__((address_space(3))) u32*)l, 16, 0, 0);
}

// ---------------- reductions ----------------
__device__ __forceinline__ float wave_sum(float v) {
#pragma unroll
    for (int o = 32; o > 0; o >>= 1) v += __shfl_down(v, o, 64);
    return v;
}
__device__ __forceinline__ float wave_max(float v) {
#pragma unroll
    for (int o = 32; o > 0; o >>= 1) v = fmaxf(v, __shfl_down(v, o, 64));
    return v;
}
__device__ __forceinline__ float blk_sum256(float v, float* sm) {
    v = wave_sum(v);
    int lane = threadIdx.x & 63, w = threadIdx.x >> 6;
    __syncthreads();
    if (lane == 0) sm[w] = v;
    __syncthreads();
    return sm[0] + sm[1] + sm[2] + sm[3];
}
__device__ __forceinline__ float blk_sum1024(float v, float* sm) {
    v = wave_sum(v);
    int lane = threadIdx.x & 63, w = threadIdx.x >> 6;
    __syncthreads();
    if (lane == 0) sm[w] = v;
    __syncthreads();
    float r = 0.f;
#pragma unroll
    for (int i = 0; i < 16; i++) r += sm[i];
    return r;
}
__device__ __forceinline__ float blk_max1024(float v, float* sm) {
    v = wave_max(v);
    int lane = threadIdx.x & 63, w = threadIdx.x >> 6;
    __syncthreads();
    if (lane == 0) sm[w] = v;
    __syncthreads();
    float r = -1e30f;
#pragma unroll
    for (int i = 0; i < 16; i++) r = fmaxf(r, sm[i]);
    return r;
}

// ---------------- embedding + LN (writes h fp32 and hb bf16) ----------------
__global__ __launch_bounds__(256) void k_embed_ln(
    const float* __restrict__ WE, const float* __restrict__ PE,
    const float* __restrict__ g, const float* __restrict__ bta,
    const int* __restrict__ ids, float* __restrict__ h, u16* __restrict__ hb)
{
    __shared__ float sm[4];
    int tok = blockIdx.x;
    int s = tok & (SEQ - 1);
    int id = ids[tok];
    float x[3];
#pragma unroll
    for (int j = 0; j < 3; j++) {
        int d = threadIdx.x + j * 256;
        x[j] = WE[(size_t)id * HDIM + d] + PE[(size_t)s * HDIM + d];
    }
    float s1 = blk_sum256(x[0] + x[1] + x[2], sm);
    float s2 = blk_sum256(x[0]*x[0] + x[1]*x[1] + x[2]*x[2], sm);
    float mean = s1 * (1.f / HDIM);
    float var  = s2 * (1.f / HDIM) - mean * mean;
    float inv  = rsqrtf(var + 1e-5f);
#pragma unroll
    for (int j = 0; j < 3; j++) {
        int d = threadIdx.x + j * 256;
        float v2 = (x[j] - mean) * inv * g[d] + bta[d];
        h[(size_t)tok * HDIM + d] = v2;
        hb[(size_t)tok * HDIM + d] = f2bf(v2);
    }
}

// ---------------- residual add + LN (h fp32 in place, hb bf16 out) ----------------
__global__ __launch_bounds__(256) void k_addln(
    float* __restrict__ h, const float* __restrict__ t,
    const float* __restrict__ g, const float* __restrict__ bta, u16* __restrict__ hb)
{
    __shared__ float sm[4];
    int tok = blockIdx.x;
    float x[3];
#pragma unroll
    for (int j = 0; j < 3; j++) {
        int d = threadIdx.x + j * 256;
        x[j] = h[(size_t)tok * HDIM + d] + t[(size_t)tok * HDIM + d];
    }
    float s1 = blk_sum256(x[0] + x[1] + x[2], sm);
    float s2 = blk_sum256(x[0]*x[0] + x[1]*x[1] + x[2]*x[2], sm);
    float mean = s1 * (1.f / HDIM);
    float var  = s2 * (1.f / HDIM) - mean * mean;
    float inv  = rsqrtf(var + 1e-5f);
#pragma unroll
    for (int j = 0; j < 3; j++) {
        int d = threadIdx.x + j * 256;
        float v2 = (x[j] - mean) * inv * g[d] + bta[d];
        h[(size_t)tok * HDIM + d] = v2;
        hb[(size_t)tok * HDIM + d] = f2bf(v2);
    }
}

// ---------------- transpose + fp32->bf16: W[K][N] -> dst[N][K] ----------------
// grid (N/32, K/32), 256 threads
__global__ __launch_bounds__(256) void k_cvtT(
    const float* __restrict__ W, u16* __restrict__ dst, int K, int N)
{
    __shared__ float t[32][33];
    int n0 = blockIdx.x * 32, k0 = blockIdx.y * 32;
    int c = threadIdx.x & 31, r8 = threadIdx.x >> 5;
#pragma unroll
    for (int p = 0; p < 4; p++) {
        int k = r8 + p * 8;
        t[k][c] = W[(size_t)(k0 + k) * N + n0 + c];
    }
    __syncthreads();
#pragma unroll
    for (int p = 0; p < 2; p++) {
        int idx = threadIdx.x + p * 256;       // 0..511 over 32 n-rows x 16 k-pairs
        int n = idx >> 4, kp = idx & 15;
        float a = t[kp*2][n], b = t[kp*2+1][n];
        u32 pk = (u32)f2bf(a) | ((u32)f2bf(b) << 16);
        u32* d = (u32*)(dst + (size_t)(n0 + n) * K + k0);
        d[kp] = pk;
    }
}

// ---------------- MFMA GEMM: C[M,N] = A[M,K](bf16) @ BT[N,K]^T(bf16) ----------------
// MODE 0: C fp32 [M,N] (+bias b0)
// MODE 1: QKV split -> bf16 planes [3][B,NH,S,DH], biases b0/b1/b2
// MODE 2: GELU -> bf16 [M,N]
template<int BM, int BN, int MODE>
__global__ __launch_bounds__(256) void k_gemm_mfma(
    const u16* __restrict__ A, const u16* __restrict__ BT,
    const float* __restrict__ b0, const float* __restrict__ b1, const float* __restrict__ b2,
    void* __restrict__ C, int K, int N)
{
    __shared__ u16 As[BM * 32];
    __shared__ u16 Bs[BN * 32];
    const int tid = threadIdx.x, lane = tid & 63, w = tid >> 6;
    const int bm = blockIdx.y * BM, bn = blockIdx.x * BN;
    constexpr int MT = BM / 32, NT = BN / 32;      // mfma tiles per wave
    constexpr int AR = BM / 4, BR = BN / 4;        // staging rows per wave
    constexpr int AI = AR / 16, BI = BR / 16;      // lds-dma instrs per wave
    const int wm = (w & 1) * (BM / 2), wn = (w >> 1) * (BN / 2);

    f32x4 acc[MT][NT];
#pragma unroll
    for (int mi = 0; mi < MT; mi++)
#pragma unroll
        for (int ni = 0; ni < NT; ni++) acc[mi][ni] = (f32x4){0.f, 0.f, 0.f, 0.f};

    const u16* ag = A  + (size_t)(bm + w * AR + (lane >> 2)) * K + (lane & 3) * 8;
    const u16* bg = BT + (size_t)(bn + w * BR + (lane >> 2)) * K + (lane & 3) * 8;
    u16* al = As + w * AR * 32;
    u16* bl = Bs + w * BR * 32;
    const int fr = lane & 15, fq = (lane >> 4) * 8;

    for (int k0 = 0; k0 < K; k0 += 32) {
#pragma unroll
        for (int i = 0; i < AI; i++) gload16(ag + (size_t)i * 16 * K + k0, al + i * 512);
#pragma unroll
        for (int i = 0; i < BI; i++) gload16(bg + (size_t)i * 16 * K + k0, bl + i * 512);
        __syncthreads();
        bf16x8 af[MT], bf[NT];
#pragma unroll
        for (int mi = 0; mi < MT; mi++)
            af[mi] = *(const bf16x8*)(As + (wm + mi * 16 + fr) * 32 + fq);
#pragma unroll
        for (int ni = 0; ni < NT; ni++)
            bf[ni] = *(const bf16x8*)(Bs + (wn + ni * 16 + fr) * 32 + fq);
#pragma unroll
        for (int mi = 0; mi < MT; mi++)
#pragma unroll
            for (int ni = 0; ni < NT; ni++)
                acc[mi][ni] = __builtin_amdgcn_mfma_f32_16x16x32_bf16(af[mi], bf[ni], acc[mi][ni], 0, 0, 0);
        __syncthreads();
    }

#pragma unroll
    for (int mi = 0; mi < MT; mi++) {
        int m_base = bm + wm + mi * 16 + (lane >> 4) * 4;
#pragma unroll
        for (int ni = 0; ni < NT; ni++) {
            int n_g = bn + wn + ni * 16 + (lane & 15);
            const float* bp = b0; int nn = n_g; int which = 0;
            if (MODE == 1) {
                if (n_g >= 1536)      { bp = b2; nn = n_g - 1536; which = 2; }
                else if (n_g >= 768)  { bp = b1; nn = n_g - 768;  which = 1; }
            }
            float bias = bp[nn];
#pragma unroll
            for (int r = 0; r < 4; r++) {
                int m_g = m_base + r;
                float val = acc[mi][ni][r] + bias;
                if (MODE == 0) {
                    ((float*)C)[(size_t)m_g * N + n_g] = val;
                } else if (MODE == 1) {
                    int bb = m_g >> 10, ss = m_g & 1023;
                    int hh = nn >> 6, dd = nn & 63;
                    ((u16*)C)[(size_t)which * PLANE + (((size_t)bb * NHEAD + hh) * SEQ + ss) * DHEAD + dd] = f2bf(val);
                } else {
                    val = 0.5f * val * (1.f + erff(val * 0.70710678118f));
                    ((u16*)C)[(size_t)m_g * N + n_g] = f2bf(val);
                }
            }
        }
    }
}

// ---------------- banded local attention: 64 q rows/block, 4-way key split ----------------
// window per token: keys [p-256, p+256]; per 64-row tile: 576 keys = 6 chunks of 96
__global__ __launch_bounds__(256) void k_attn(
    const u16* __restrict__ qkv, const int* __restrict__ mask, u16* __restrict__ abuf)
{
    __shared__ float ks[96][64];
    __shared__ float vs[96][64];
    __shared__ int   ms[96];
    __shared__ float ml[256][2];
    const int tid = threadIdx.x;
    int blk = blockIdx.x;                 // B*NH*16
    int qt = blk & 15;
    int hh = (blk >> 4) % NHEAD;
    int b  = blk / (16 * NHEAD);
    int i = tid & 63, t = tid >> 6;
    int q0 = qt * 64, qpos = q0 + i;

    const u16* qp = qkv + (((size_t)b * NHEAD + hh) * SEQ) * DHEAD;
    const u16* kp = qp + PLANE;
    const u16* vp = qp + 2 * PLANE;

    float4 qv[16];
    {
        const uint2* q2 = (const uint2*)(qp + (size_t)qpos * DHEAD);
#pragma unroll
        for (int c = 0; c < 16; c++) {
            uint2 u = q2[c];
            qv[c] = make_float4(bflo(u.x), bfhi(u.x), bflo(u.y), bfhi(u.y));
        }
    }
    float4 av[16];
#pragma unroll
    for (int c = 0; c < 16; c++) av[c] = make_float4(0.f, 0.f, 0.f, 0.f);
    float mrun = -1e30f, l = 0.f;

    for (int ch = 0; ch < 6; ch++) {
        int kbase = q0 - 256 + ch * 96;
        __syncthreads();
#pragma unroll
        for (int it = 0; it < 6; it++) {
            int idx = tid + it * 256;          // 96 rows x 16 uint2-slots
            int r = idx >> 4, c4 = (idx & 15) * 4;
            int kq = kbase + r;
            bool in = (kq >= 0) && (kq < SEQ);
            uint2 uk = in ? *(const uint2*)(kp + (size_t)kq * DHEAD + c4) : make_uint2(0u, 0u);
            uint2 uv = in ? *(const uint2*)(vp + (size_t)kq * DHEAD + c4) : make_uint2(0u, 0u);
            ks[r][c4+0] = bflo(uk.x); ks[r][c4+1] = bfhi(uk.x);
            ks[r][c4+2] = bflo(uk.y); ks[r][c4+3] = bfhi(uk.y);
            vs[r][c4+0] = bflo(uv.x); vs[r][c4+1] = bfhi(uv.x);
            vs[r][c4+2] = bflo(uv.y); vs[r][c4+3] = bfhi(uv.y);
        }
        if (tid < 96) {
            int kq = kbase + tid;
            ms[tid] = (kq >= 0 && kq < SEQ) ? mask[b * SEQ + kq] : 0;
        }
        __syncthreads();
        for (int j = 0; j < 24; j++) {
            int lr = t * 24 + j;
            int kj = ch * 96 + lr;                // span coord; valid iff kj-i in [0,512]
            bool ok = (kj >= i) && (kj <= i + 512) && (ms[lr] != 0);
            float d0 = 0.f;
#pragma unroll
            for (int c = 0; c < 16; c++) {
                float4 k4 = *(const float4*)&ks[lr][c * 4];
                d0 = fmaf(qv[c].x, k4.x, d0); d0 = fmaf(qv[c].y, k4.y, d0);
                d0 = fmaf(qv[c].z, k4.z, d0); d0 = fmaf(qv[c].w, k4.w, d0);
            }
            if (ok) {
                float s = d0 * 0.125f;
                float mn = fmaxf(mrun, s);
                float scale = __expf(mrun - mn);
                float p = __expf(s - mn);
                l = l * scale + p;
#pragma unroll
                for (int c = 0; c < 16; c++) {
                    float4 v4 = *(const float4*)&vs[lr][c * 4];
                    av[c].x = av[c].x * scale + p * v4.x;
                    av[c].y = av[c].y * scale + p * v4.y;
                    av[c].z = av[c].z * scale + p * v4.z;
                    av[c].w = av[c].w * scale + p * v4.w;
                }
                mrun = mn;
            }
        }
    }

    __syncthreads();
    ml[tid][0] = mrun; ml[tid][1] = l;
    __syncthreads();
    float M = -1e30f;
#pragma unroll
    for (int tt = 0; tt < 4; tt++) M = fmaxf(M, ml[i + tt * 64][0]);
    float myscale = __expf(mrun - M);

    float (*acc)[68] = (float(*)[68])ks;   // 64x68 fp32 = 17.4KB, fits inside ks
    for (int tt = 0; tt < 4; tt++) {
        if (t == tt) {
            if (tt == 0) {
#pragma unroll
                for (int c = 0; c < 16; c++) {
                    float4 o;
                    o.x = av[c].x * myscale; o.y = av[c].y * myscale;
                    o.z = av[c].z * myscale; o.w = av[c].w * myscale;
                    *(float4*)&acc[i][c * 4] = o;
                }
            } else {
#pragma unroll
                for (int c = 0; c < 16; c++) {
                    float4 o = *(float4*)&acc[i][c * 4];
                    o.x += av[c].x * myscale; o.y += av[c].y * myscale;
                    o.z += av[c].z * myscale; o.w += av[c].w * myscale;
                    *(float4*)&acc[i][c * 4] = o;
                }
            }
        }
        __syncthreads();
    }

    // output: thread -> row tid>>2, 16-dim segment (tid&3)*16
    int row = tid >> 2, sg = (tid & 3) * 16;
    float Mr = -1e30f;
#pragma unroll
    for (int tt = 0; tt < 4; tt++) Mr = fmaxf(Mr, ml[row + tt * 64][0]);
    float Lr = 0.f;
#pragma unroll
    for (int tt = 0; tt < 4; tt++) Lr += __expf(ml[row + tt * 64][0] - Mr) * ml[row + tt * 64][1];
    float inv = 1.f / Lr;
    u32 us[8];
#pragma unroll
    for (int c = 0; c < 8; c++) {
        float a0 = acc[row][sg + c * 2]     * inv;
        float a1 = acc[row][sg + c * 2 + 1] * inv;
        us[c] = (u32)f2bf(a0) | ((u32)f2bf(a1) << 16);
    }
    u16* orow = abuf + ((size_t)(b * SEQ + q0 + row)) * HDIM + hh * DHEAD + sg;
    ((uint4*)orow)[0] = make_uint4(us[0], us[1], us[2], us[3]);
    ((uint4*)orow)[1] = make_uint4(us[4], us[5], us[6], us[7]);
}

// ---------------- attention-pool head ----------------
__global__ __launch_bounds__(1024) void k_pool(
    const float* __restrict__ h, const float* __restrict__ aw,
    const float* __restrict__ Wc, const float* __restrict__ bc,
    float* __restrict__ out)
{
    __shared__ float aws[HDIM];
    __shared__ float ps[SEQ];
    __shared__ float red[16];
    int b = blockIdx.x;
    for (int d = threadIdx.x; d < HDIM; d += 1024) aws[d] = aw[d];
    __syncthreads();
    const float* hb = h + (size_t)b * SEQ * HDIM;
    int s = threadIdx.x;
    float sc = 0.f;
    const float4* hr = (const float4*)(hb + (size_t)s * HDIM);
#pragma unroll 4
    for (int c = 0; c < HDIM / 4; c++) {
        float4 x = hr[c];
        sc += x.x * aws[4*c] + x.y * aws[4*c+1] + x.z * aws[4*c+2] + x.w * aws[4*c+3];
    }
    float mx = blk_max1024(sc, red);
    float e = __expf(sc - mx);
    float tot = blk_sum1024(e, red);
    ps[s] = e / tot;
    __syncthreads();
    float outv = 0.f;
    if (threadIdx.x < HDIM) {
        int d = threadIdx.x;
        float pd = 0.f;
        for (int ss = 0; ss < SEQ; ss++) pd += hb[(size_t)ss * HDIM + d] * ps[ss];
        outv = pd * Wc[d];
    }
    float total = blk_sum1024(outv, red);
    if (threadIdx.x == 0) out[b] = total + bc[0];
}

// ---------------- launcher ----------------
extern "C" void kernel_launch(void* const* d_in, const int* in_sizes, int n_in,
                              void* d_out, int out_size, void* d_ws, size_t ws_size,
                              hipStream_t stream)
{
    const float* WE    = (const float*)d_in[0];
    const float* PE    = (const float*)d_in[1];
    const float* Eg    = (const float*)d_in[2];
    const float* Eb    = (const float*)d_in[3];
    const float* Wq    = (const float*)d_in[4];
    const float* bq    = (const float*)d_in[5];
    const float* Wk    = (const float*)d_in[6];
    const float* bk    = (const float*)d_in[7];
    const float* Wv    = (const float*)d_in[8];
    const float* bv    = (const float*)d_in[9];
    const float* Wo    = (const float*)d_in[10];
    const float* bo    = (const float*)d_in[11];
    const float* g1    = (const float*)d_in[12];
    const float* beta1 = (const float*)d_in[13];
    const float* W1    = (const float*)d_in[14];
    const float* b1    = (const float*)d_in[15];
    const float* W2    = (const float*)d_in[16];
    const float* b2    = (const float*)d_in[17];
    const float* g2    = (const float*)d_in[18];
    const float* beta2 = (const float*)d_in[19];
    const float* aw    = (const float*)d_in[20];
    const float* Wc    = (const float*)d_in[21];
    const float* bc    = (const float*)d_in[22];
    const int* ids     = (const int*)d_in[23];
    const int* msk     = (const int*)d_in[24];

    char* base = (char*)d_ws;
    float* h    = (float*)base;                               base += (size_t)MTOK * HDIM * 4;   // 12.6MB
    float* tbuf = (float*)base;                               base += (size_t)MTOK * HDIM * 4;   // 12.6MB
    u16*   hb   = (u16*)base;                                 base += (size_t)MTOK * HDIM * 2;   // 6.3MB
    u16*   X    = (u16*)base;                                 base += (size_t)MTOK * FFDIM * 2;  // 25.2MB
    u16*   qkv  = X;                                          // 3 planes of PLANE
    u16*   abuf = X + 3 * PLANE;                              // [B,S,H] bf16
    u16*   mid  = X;                                          // FF1 out aliases qkv/abuf (dead)
    u16*   wqkvT = (u16*)base;                                base += (size_t)HDIM * 2304 * 2;   // 3.5MB
    u16*   woT   = (u16*)base;                                base += (size_t)HDIM * HDIM * 2;   // 1.2MB
    u16*   w1T   = (u16*)base;                                base += (size_t)FFDIM * HDIM * 2;  // 4.7MB
    u16*   w2T   = (u16*)base;                                base += (size_t)HDIM * FFDIM * 2;  // 4.7MB

    k_embed_ln<<<MTOK, 256, 0, stream>>>(WE, PE, Eg, Eb, ids, h, hb);

    for (int l = 0; l < LAYERS; l++) {
        const float* Wql = Wq + (size_t)l * HDIM * HDIM;
        const float* Wkl = Wk + (size_t)l * HDIM * HDIM;
        const float* Wvl = Wv + (size_t)l * HDIM * HDIM;
        const float* Wol = Wo + (size_t)l * HDIM * HDIM;
        const float* W1l = W1 + (size_t)l * HDIM * FFDIM;
        const float* W2l = W2 + (size_t)l * FFDIM * HDIM;

        k_cvtT<<<dim3(24, 24), 256, 0, stream>>>(Wql, wqkvT,                    HDIM, HDIM);
        k_cvtT<<<dim3(24, 24), 256, 0, stream>>>(Wkl, wqkvT + (size_t)HDIM*HDIM,   HDIM, HDIM);
        k_cvtT<<<dim3(24, 24), 256, 0, stream>>>(Wvl, wqkvT + (size_t)2*HDIM*HDIM, HDIM, HDIM);
        k_cvtT<<<dim3(24, 24), 256, 0, stream>>>(Wol, woT, HDIM, HDIM);
        k_cvtT<<<dim3(96, 24), 256, 0, stream>>>(W1l, w1T, HDIM, FFDIM);
        k_cvtT<<<dim3(24, 96), 256, 0, stream>>>(W2l, w2T, FFDIM, HDIM);

        // QKV fused: [4096,768] @ [768,2304]
        k_gemm_mfma<128, 128, 1><<<dim3(2304/128, MTOK/128), 256, 0, stream>>>(
            hb, wqkvT, bq + l*HDIM, bk + l*HDIM, bv + l*HDIM, qkv, HDIM, 2304);
        k_attn<<<BATCH * NHEAD * (SEQ/64), 256, 0, stream>>>(qkv, msk, abuf);
        // attn out proj: [4096,768] @ [768,768] -> fp32
        k_gemm_mfma<64, 64, 0><<<dim3(HDIM/64, MTOK/64), 256, 0, stream>>>(
            abuf, woT, bo + l*HDIM, nullptr, nullptr, tbuf, HDIM, HDIM);
        k_addln<<<MTOK, 256, 0, stream>>>(h, tbuf, g1 + l*HDIM, beta1 + l*HDIM, hb);
        // FF1 + gelu: [4096,768] @ [768,3072] -> bf16
        k_gemm_mfma<128, 128, 2><<<dim3(FFDIM/128, MTOK/128), 256, 0, stream>>>(
            hb, w1T, b1 + l*FFDIM, nullptr, nullptr, mid, HDIM, FFDIM);
        // FF2: [4096,3072] @ [3072,768] -> fp32
        k_gemm_mfma<64, 64, 0><<<dim3(HDIM/64, MTOK/64), 256, 0, stream>>>(
            mid, w2T, b2 + l*HDIM, nullptr, nullptr, tbuf, FFDIM, HDIM);
        k_addln<<<MTOK, 256, 0, stream>>>(h, tbuf, g2 + l*HDIM, beta2 + l*HDIM, hb);
    }

    k_pool<<<BATCH, 1024, 0, stream>>>(h, aw, Wc, bc, (float*)d_out);
}